// Round 4
// baseline (163.463 us; speedup 1.0000x reference)
//
#include <hip/hip_runtime.h>
#include <hip/hip_bf16.h>

// 8-layer MLP, B=131072, fused. R4 vs R3:
//  - layers 1..6 use mfma_f32_32x32x16_bf16 (half the MFMA instrs, 2495 vs
//    2075 TF ceiling). acc = 2x2 f32x16 = 64 VGPR (same as before).
//  - layer 7 MFMA-ized: K-split across 4 waves (2 kk-slices each, 16x16x32),
//    partial f32 reduce through LDS. Removes ~300 VALU/wave + w7s staging.
//  - layer 0 vectorized: feature-pair per thread, cvt_pk, b32 LDS writes.
//  - launch_bounds(256,4): 4 blocks/CU (LDS 38.4KB x4 fits 160KB).

#define HID 256
#define BM 64
#define NBLK 2048
#define HPITCH 264     // +8 pad: read/write LDS patterns hit structural minimum

typedef __attribute__((ext_vector_type(8))) short bf16x8;
typedef __attribute__((ext_vector_type(8))) unsigned short u16x8;
typedef __attribute__((ext_vector_type(4))) unsigned short u16x4;
typedef __attribute__((ext_vector_type(4))) float f32x4;
typedef __attribute__((ext_vector_type(16))) float f32x16;

__device__ __forceinline__ unsigned cvt_pk_bf16(float lo, float hi) {
    unsigned r;
    asm("v_cvt_pk_bf16_f32 %0, %1, %2" : "=v"(r) : "v"(lo), "v"(hi));
    return r;
}

struct WPtrs { const float* w[6]; const float* w7; };

// Pack W1..W6 as 32x32x16 A-frags:
//   frag (L,w,kk,ft): lane l, elem j = W_L[64w+32ft+(l&31)][16kk+8(l>>5)+j]
//   stored at Wp[tid*8], tid = (((L*4+w)*16+kk)*2+ft)*64 + l  (768 frags, 786KB)
// Pack W7 as 16x16x32 A-frags (rows 3..15 zero):
//   frag kk: lane l, elem j = W7[(l&15)][32kk+8(l>>4)+j], at Wp+393216+t*8
__global__ void pack_w_kernel(WPtrs wp, unsigned short* __restrict__ Wp) {
    int tid = blockIdx.x * 256 + threadIdx.x;
    if (tid < 49152) {
        int l  = tid & 63;
        int ft = (tid >> 6) & 1;
        int kk = (tid >> 7) & 15;
        int w  = (tid >> 11) & 3;
        int L  = tid >> 13;
        int n  = 64 * w + 32 * ft + (l & 31);
        int k0 = 16 * kk + 8 * (l >> 5);
        const float* src = wp.w[L] + n * HID + k0;
        u16x8 v;
#pragma unroll
        for (int j = 0; j < 8; ++j) {
            union { float f; unsigned u; } c; c.f = src[j];
            unsigned r = c.u + 0x7fffu + ((c.u >> 16) & 1u);  // RNE
            v[j] = (unsigned short)(r >> 16);
        }
        *(u16x8*)(Wp + (size_t)tid * 8) = v;
    } else if (tid < 49664) {
        int t  = tid - 49152;
        int l  = t & 63;
        int kk = t >> 6;                 // 0..7
        int n  = l & 15;
        int k0 = 32 * kk + 8 * (l >> 4);
        u16x8 v;
#pragma unroll
        for (int j = 0; j < 8; ++j) {
            unsigned short s = 0;
            if (n < 3) {
                union { float f; unsigned u; } c; c.f = wp.w7[n * HID + k0 + j];
                s = (unsigned short)((c.u + 0x7fffu + ((c.u >> 16) & 1u)) >> 16);
            }
            v[j] = s;
        }
        *(u16x8*)(Wp + 393216 + (size_t)t * 8) = v;
    }
}

__launch_bounds__(256, 4)
__global__ void mlp_fused_kernel(const float* __restrict__ x,
                                 const float* __restrict__ W0,
                                 const unsigned short* __restrict__ Wp,
                                 float* __restrict__ out) {
    __shared__ __align__(16) unsigned short Hs[BM][HPITCH];  // 33,792 B
    __shared__ __align__(16) float Ps[4][64][4];             // 4,096 B (layer-7 partials)
    __shared__ float xsf[2 * BM];                            // 512 B

    const int tid = threadIdx.x;
    const int l   = tid & 63;
    const int w   = tid >> 6;
    const long r0 = (long)blockIdx.x * BM;

    // weight stream base: frags for (L, wave w), lane l
    const unsigned short* wbl = Wp + (size_t)w * 16384 + (size_t)l * 8;

    // issue first weight frags now (land during layer-0 work)
    bf16x8 wb[2][2];
    wb[0][0] = *(const bf16x8*)(wbl);
    wb[0][1] = *(const bf16x8*)(wbl + 512);

    // ---- stage x ----
    if (tid < 2 * BM) xsf[tid] = x[r0 * 2 + tid];
    // layer-0: thread owns feature pair fp, half the rows
    const int fp   = (tid & 127) * 2;
    const int half = tid >> 7;
    f32x4 w0v = *(const f32x4*)(W0 + 2 * fp);  // [fp][0],[fp][1],[fp+1][0],[fp+1][1]
    __syncthreads();

    // ---- layer 0: h = relu(x @ W0.T) -> bf16 LDS ----
    const int mb = 32 * half;
#pragma unroll
    for (int i = 0; i < 32; ++i) {
        int m = mb + i;
        float x0 = xsf[2 * m], x1 = xsf[2 * m + 1];
        float ha = fmaf(x0, w0v[0], x1 * w0v[1]);
        float hb = fmaf(x0, w0v[2], x1 * w0v[3]);
        *(unsigned*)(&Hs[m][fp]) = cvt_pk_bf16(fmaxf(0.f, ha), fmaxf(0.f, hb));
    }
    __syncthreads();

    // ---- layers 1..6: 32x32x16 MFMA; wave w owns features [64w,64w+64) ----
    const int c  = l & 31;     // batch col within 32-tile / A row
    const int hi = l >> 5;
    for (int L = 0; L < 6; ++L) {
        f32x16 acc[2][2];      // [ft][mt]
#pragma unroll
        for (int ft = 0; ft < 2; ++ft)
#pragma unroll
            for (int mt = 0; mt < 2; ++mt)
#pragma unroll
                for (int j = 0; j < 16; ++j) acc[ft][mt][j] = 0.f;

#pragma unroll
        for (int kk = 0; kk < 16; ++kk) {
            const int cur = kk & 1, nxt = cur ^ 1;
            if (kk < 15) {
                wb[nxt][0] = *(const bf16x8*)(wbl + L * 65536 + (kk + 1) * 1024);
                wb[nxt][1] = *(const bf16x8*)(wbl + L * 65536 + (kk + 1) * 1024 + 512);
            } else if (L < 5) {
                wb[nxt][0] = *(const bf16x8*)(wbl + (L + 1) * 65536);
                wb[nxt][1] = *(const bf16x8*)(wbl + (L + 1) * 65536 + 512);
            }
            bf16x8 a0 = *(const bf16x8*)(&Hs[c][16 * kk + 8 * hi]);
            bf16x8 a1 = *(const bf16x8*)(&Hs[32 + c][16 * kk + 8 * hi]);
            acc[0][0] = __builtin_amdgcn_mfma_f32_32x32x16_bf16(wb[cur][0], a0, acc[0][0], 0, 0, 0);
            acc[0][1] = __builtin_amdgcn_mfma_f32_32x32x16_bf16(wb[cur][0], a1, acc[0][1], 0, 0, 0);
            acc[1][0] = __builtin_amdgcn_mfma_f32_32x32x16_bf16(wb[cur][1], a0, acc[1][0], 0, 0, 0);
            acc[1][1] = __builtin_amdgcn_mfma_f32_32x32x16_bf16(wb[cur][1], a1, acc[1][1], 0, 0, 0);
        }
        __syncthreads();   // all Hs reads done; overwrite in place
        // D: lane l holds batch row 32mt+c, features 64w+32ft+8g+4hi+{0..3} (reg 4g+r)
#pragma unroll
        for (int ft = 0; ft < 2; ++ft)
#pragma unroll
            for (int mt = 0; mt < 2; ++mt) {
                f32x16 v = acc[ft][mt];
#pragma unroll
                for (int g = 0; g < 4; ++g) {
                    union { unsigned u[2]; u16x4 s; } pk;
                    pk.u[0] = cvt_pk_bf16(fmaxf(0.f, v[4 * g]),     fmaxf(0.f, v[4 * g + 1]));
                    pk.u[1] = cvt_pk_bf16(fmaxf(0.f, v[4 * g + 2]), fmaxf(0.f, v[4 * g + 3]));
                    *(u16x4*)(&Hs[32 * mt + c][64 * w + 32 * ft + 8 * g + 4 * hi]) = pk.s;
                }
            }
        __syncthreads();
    }

    // ---- layer 7 via 16x16x32 MFMA: wave w does K slices {2w, 2w+1} ----
    const int lr = l & 15, lg = l >> 4;
    const unsigned short* w7b = Wp + 393216 + (size_t)l * 8;
    bf16x8 w7f0 = *(const bf16x8*)(w7b + (2 * w) * 512);
    bf16x8 w7f1 = *(const bf16x8*)(w7b + (2 * w + 1) * 512);
    f32x4 acc7[4];
#pragma unroll
    for (int mt = 0; mt < 4; ++mt) acc7[mt] = (f32x4){0.f, 0.f, 0.f, 0.f};
#pragma unroll
    for (int mt = 0; mt < 4; ++mt) {
        bf16x8 a = *(const bf16x8*)(&Hs[16 * mt + lr][32 * (2 * w) + 8 * lg]);
        acc7[mt] = __builtin_amdgcn_mfma_f32_16x16x32_bf16(w7f0, a, acc7[mt], 0, 0, 0);
        bf16x8 b = *(const bf16x8*)(&Hs[16 * mt + lr][32 * (2 * w + 1) + 8 * lg]);
        acc7[mt] = __builtin_amdgcn_mfma_f32_16x16x32_bf16(w7f1, b, acc7[mt], 0, 0, 0);
    }
    // lanes lg==0 hold features 0..3 (3 = zero row) for batch row 16mt+lr
    if (lg == 0) {
#pragma unroll
        for (int mt = 0; mt < 4; ++mt)
            *(f32x4*)(&Ps[w][16 * mt + lr][0]) = acc7[mt];
    }
    __syncthreads();
    // ---- reduce 4 wave-partials + sigmoid; out is [64 rows][3] coalesced ----
    if (tid < 192) {
        int row = tid / 3, o = tid - 3 * row;
        float s = Ps[0][row][o] + Ps[1][row][o] + Ps[2][row][o] + Ps[3][row][o];
        out[r0 * 3 + tid] = 1.f / (1.f + __expf(-s));
    }
}

extern "C" void kernel_launch(void* const* d_in, const int* in_sizes, int n_in,
                              void* d_out, int out_size, void* d_ws, size_t ws_size,
                              hipStream_t stream) {
    const float* x  = (const float*)d_in[0];
    const float* W0 = (const float*)d_in[1];
    WPtrs wp;
    for (int i = 0; i < 6; ++i) wp.w[i] = (const float*)d_in[2 + i];
    wp.w7 = (const float*)d_in[8];
    float* out = (float*)d_out;
    unsigned short* Wp = (unsigned short*)d_ws;   // 794,624 B used

    pack_w_kernel<<<194, 256, 0, stream>>>(wp, Wp);
    mlp_fused_kernel<<<NBLK, 256, 0, stream>>>(x, W0, Wp, out);
}

// Round 6
// 159.668 us; speedup vs baseline: 1.0238x; 1.0238x over previous
//
#include <hip/hip_runtime.h>
#include <hip/hip_bf16.h>

// 8-layer MLP, B=131072, fused. R5 vs R4:
//  - BM=128, 512 threads, 8 waves: waves w and w+4 consume the SAME 32KB
//    weight slice (feature block w&3) for different row halves -> L1 dedup
//    halves per-CU L2 weight traffic (R4 post-mortem: weight path ~25 B/cyc/CU
//    ~45% of L2 ceiling with all CUs on the same lines = suspected pin).
//  - LDS 75KB -> exactly 2 blocks/CU (16 waves, 50% cap).
//  - everything else (32x32x16 MFMA, reg-dbuf weight prefetch, cvt_pk epilogue,
//    MFMA layer 7) carried over from R4.

#define HID 256
#define BM 128
#define NBLK 1024      // 131072 / 128
#define HPITCH 264     // pad: 4-way max on b128 reads (1.58x, minor per m136)

typedef __attribute__((ext_vector_type(8))) short bf16x8;
typedef __attribute__((ext_vector_type(8))) unsigned short u16x8;
typedef __attribute__((ext_vector_type(4))) unsigned short u16x4;
typedef __attribute__((ext_vector_type(4))) float f32x4;
typedef __attribute__((ext_vector_type(16))) float f32x16;

__device__ __forceinline__ unsigned cvt_pk_bf16(float lo, float hi) {
    unsigned r;
    asm("v_cvt_pk_bf16_f32 %0, %1, %2" : "=v"(r) : "v"(lo), "v"(hi));
    return r;
}

struct WPtrs { const float* w[6]; const float* w7; };

// Pack W1..W6 as 32x32x16 A-frags (same as R4):
//   frag (L,fw,kk,ft): lane l, elem j = W_L[64fw+32ft+(l&31)][16kk+8(l>>5)+j]
//   at Wp[(((L*4+fw)*16+kk)*2+ft)*64*8 + l*8]
// W7 as 16x16x32 A-frags (rows 3..15 zero) at Wp+393216.
__global__ void pack_w_kernel(WPtrs wp, unsigned short* __restrict__ Wp) {
    int tid = blockIdx.x * 256 + threadIdx.x;
    if (tid < 49152) {
        int l  = tid & 63;
        int ft = (tid >> 6) & 1;
        int kk = (tid >> 7) & 15;
        int fw = (tid >> 11) & 3;
        int L  = tid >> 13;
        int n  = 64 * fw + 32 * ft + (l & 31);
        int k0 = 16 * kk + 8 * (l >> 5);
        const float* src = wp.w[L] + n * HID + k0;
        u16x8 v;
#pragma unroll
        for (int j = 0; j < 8; ++j) {
            union { float f; unsigned u; } c; c.f = src[j];
            unsigned r = c.u + 0x7fffu + ((c.u >> 16) & 1u);  // RNE
            v[j] = (unsigned short)(r >> 16);
        }
        *(u16x8*)(Wp + (size_t)tid * 8) = v;
    } else if (tid < 49664) {
        int t  = tid - 49152;
        int l  = t & 63;
        int kk = t >> 6;                 // 0..7
        int n  = l & 15;
        int k0 = 32 * kk + 8 * (l >> 4);
        u16x8 v;
#pragma unroll
        for (int j = 0; j < 8; ++j) {
            unsigned short s = 0;
            if (n < 3) {
                union { float f; unsigned u; } c; c.f = wp.w7[n * HID + k0 + j];
                s = (unsigned short)((c.u + 0x7fffu + ((c.u >> 16) & 1u)) >> 16);
            }
            v[j] = s;
        }
        *(u16x8*)(Wp + 393216 + (size_t)t * 8) = v;
    }
}

__launch_bounds__(512, 4)
__global__ void mlp_fused_kernel(const float* __restrict__ x,
                                 const float* __restrict__ W0,
                                 const unsigned short* __restrict__ Wp,
                                 float* __restrict__ out) {
    __shared__ __align__(16) unsigned short Hs[BM][HPITCH];  // 67,584 B
    __shared__ __align__(16) float Ps[4][BM][4];             // 8,192 B
    __shared__ float xsf[2 * BM];                            // 1,024 B

    const int tid = threadIdx.x;
    const int l   = tid & 63;
    const int w   = tid >> 6;        // 0..7
    const int fw  = w & 3;           // feature slice [64fw, 64fw+64)
    const int rb  = (w >> 2) * 64;   // row half base
    const long r0 = (long)blockIdx.x * BM;

    // weight stream: waves w and w+4 read the SAME addresses (L1 dedup)
    const unsigned short* wbl = Wp + (size_t)fw * 16384 + (size_t)l * 8;

    bf16x8 wb[2][2];
    wb[0][0] = *(const bf16x8*)(wbl);
    wb[0][1] = *(const bf16x8*)(wbl + 512);

    // ---- stage x ----
    if (tid < 2 * BM) xsf[tid] = x[r0 * 2 + tid];
    const int fp = (tid & 127) * 2;          // feature pair
    const int q  = tid >> 7;                 // row quarter
    f32x4 w0v = *(const f32x4*)(W0 + 2 * fp);
    __syncthreads();

    // ---- layer 0: relu(x @ W0.T) -> bf16 LDS ----
#pragma unroll
    for (int i = 0; i < 32; ++i) {
        int m = 32 * q + i;
        float x0 = xsf[2 * m], x1 = xsf[2 * m + 1];
        float ha = fmaf(x0, w0v[0], x1 * w0v[1]);
        float hb = fmaf(x0, w0v[2], x1 * w0v[3]);
        *(unsigned*)(&Hs[m][fp]) = cvt_pk_bf16(fmaxf(0.f, ha), fmaxf(0.f, hb));
    }
    __syncthreads();

    // ---- layers 1..6: 32x32x16 MFMA ----
    const int c  = l & 31;
    const int hi = l >> 5;
    for (int L = 0; L < 6; ++L) {
        f32x16 acc[2][2];      // [ft][mt]
#pragma unroll
        for (int ft = 0; ft < 2; ++ft)
#pragma unroll
            for (int mt = 0; mt < 2; ++mt)
#pragma unroll
                for (int j = 0; j < 16; ++j) acc[ft][mt][j] = 0.f;

#pragma unroll
        for (int kk = 0; kk < 16; ++kk) {
            const int cur = kk & 1, nxt = cur ^ 1;
            if (kk < 15) {
                wb[nxt][0] = *(const bf16x8*)(wbl + L * 65536 + (kk + 1) * 1024);
                wb[nxt][1] = *(const bf16x8*)(wbl + L * 65536 + (kk + 1) * 1024 + 512);
            } else if (L < 5) {
                wb[nxt][0] = *(const bf16x8*)(wbl + (L + 1) * 65536);
                wb[nxt][1] = *(const bf16x8*)(wbl + (L + 1) * 65536 + 512);
            }
            bf16x8 a0 = *(const bf16x8*)(&Hs[rb + c][16 * kk + 8 * hi]);
            bf16x8 a1 = *(const bf16x8*)(&Hs[rb + 32 + c][16 * kk + 8 * hi]);
            acc[0][0] = __builtin_amdgcn_mfma_f32_32x32x16_bf16(wb[cur][0], a0, acc[0][0], 0, 0, 0);
            acc[0][1] = __builtin_amdgcn_mfma_f32_32x32x16_bf16(wb[cur][0], a1, acc[0][1], 0, 0, 0);
            acc[1][0] = __builtin_amdgcn_mfma_f32_32x32x16_bf16(wb[cur][1], a0, acc[1][0], 0, 0, 0);
            acc[1][1] = __builtin_amdgcn_mfma_f32_32x32x16_bf16(wb[cur][1], a1, acc[1][1], 0, 0, 0);
        }
        __syncthreads();
        // D: lane holds batch row rb+32mt+c, features 64fw+32ft+8g+4hi+{0..3}
#pragma unroll
        for (int ft = 0; ft < 2; ++ft)
#pragma unroll
            for (int mt = 0; mt < 2; ++mt) {
                f32x16 v = acc[ft][mt];
#pragma unroll
                for (int g = 0; g < 4; ++g) {
                    union { unsigned u[2]; u16x4 s; } pk;
                    pk.u[0] = cvt_pk_bf16(fmaxf(0.f, v[4 * g]),     fmaxf(0.f, v[4 * g + 1]));
                    pk.u[1] = cvt_pk_bf16(fmaxf(0.f, v[4 * g + 2]), fmaxf(0.f, v[4 * g + 3]));
                    *(u16x4*)(&Hs[rb + 32 * mt + c][64 * fw + 32 * ft + 8 * g + 4 * hi]) = pk.s;
                }
            }
        __syncthreads();
    }

    // ---- layer 7 (16x16x32): wave w -> rows [rb,rb+64), K slices {2fw,2fw+1} ----
    const int lr = l & 15, lg = l >> 4;
    const unsigned short* w7b = Wp + 393216 + (size_t)l * 8;
    bf16x8 w7f0 = *(const bf16x8*)(w7b + (2 * fw) * 512);
    bf16x8 w7f1 = *(const bf16x8*)(w7b + (2 * fw + 1) * 512);
    f32x4 acc7[4];
#pragma unroll
    for (int mt = 0; mt < 4; ++mt) acc7[mt] = (f32x4){0.f, 0.f, 0.f, 0.f};
#pragma unroll
    for (int mt = 0; mt < 4; ++mt) {
        bf16x8 a = *(const bf16x8*)(&Hs[rb + 16 * mt + lr][32 * (2 * fw) + 8 * lg]);
        acc7[mt] = __builtin_amdgcn_mfma_f32_16x16x32_bf16(w7f0, a, acc7[mt], 0, 0, 0);
        bf16x8 b = *(const bf16x8*)(&Hs[rb + 16 * mt + lr][32 * (2 * fw + 1) + 8 * lg]);
        acc7[mt] = __builtin_amdgcn_mfma_f32_16x16x32_bf16(w7f1, b, acc7[mt], 0, 0, 0);
    }
    if (lg == 0) {
#pragma unroll
        for (int mt = 0; mt < 4; ++mt)
            *(f32x4*)(&Ps[fw][rb + 16 * mt + lr][0]) = acc7[mt];
    }
    __syncthreads();
    // ---- reduce 4 K-partials + sigmoid ----
    if (tid < 3 * BM) {
        int row = tid / 3, o = tid - 3 * row;
        float s = Ps[0][row][o] + Ps[1][row][o] + Ps[2][row][o] + Ps[3][row][o];
        out[r0 * 3 + tid] = 1.f / (1.f + __expf(-s));
    }
}

extern "C" void kernel_launch(void* const* d_in, const int* in_sizes, int n_in,
                              void* d_out, int out_size, void* d_ws, size_t ws_size,
                              hipStream_t stream) {
    const float* x  = (const float*)d_in[0];
    const float* W0 = (const float*)d_in[1];
    WPtrs wp;
    for (int i = 0; i < 6; ++i) wp.w[i] = (const float*)d_in[2 + i];
    wp.w7 = (const float*)d_in[8];
    float* out = (float*)d_out;
    unsigned short* Wp = (unsigned short*)d_ws;   // 794,624 B used

    pack_w_kernel<<<194, 256, 0, stream>>>(wp, Wp);
    mlp_fused_kernel<<<NBLK, 512, 0, stream>>>(x, W0, Wp, out);
}